// Round 4
// baseline (249.666 us; speedup 1.0000x reference)
//
#include <hip/hip_runtime.h>
#include <math.h>

// B=8, C=64, H=W=64, N=4096, N4=1024. bf16 MFMA, fp32 accumulate.
// Flash uses S^T/O^T formulation: per-lane softmax stats, shuffle-based
// P-layout transform, no LDS / no barriers in the K-loop.

typedef __bf16 bf16;
typedef __attribute__((ext_vector_type(2))) __bf16 bf16x2;
typedef __attribute__((ext_vector_type(4))) __bf16 bf16x4;
typedef __attribute__((ext_vector_type(8))) __bf16 bf16x8;
typedef __attribute__((ext_vector_type(4))) float f32x4;

union Pack2 { unsigned int u; bf16x2 v; };
union PackU { unsigned int u[4]; bf16x8 v; };

__device__ inline unsigned int pack_bf16(float a, float b) {
    Pack2 p; p.v = (bf16x2){(bf16)a, (bf16)b}; return p.u;
}

// ---------------------------------------------------------------------------
// Fused transpose-cast + 2x2 pool:
//   x (B,64,4096) fp32 -> xT (B,4096,64) bf16, xpT (B,1024,64) bf16.
// Block covers 2 spatial rows (128 n) of one batch.
// ---------------------------------------------------------------------------
__global__ __launch_bounds__(256) void transpool_kernel(const float* __restrict__ x,
                                                        bf16* __restrict__ xT,
                                                        bf16* __restrict__ xpT) {
    __shared__ float tile[128 * 65];
    const int t  = threadIdx.x;
    const int h2 = blockIdx.x;          // pooled row hp = h2
    const int b  = blockIdx.y;
    const int n0 = h2 * 128;
    #pragma unroll
    for (int i = 0; i < 32; ++i) {
        int lin = i * 256 + t;
        int n = lin & 127, c = lin >> 7;
        tile[n * 65 + c] = x[((size_t)b * 64 + c) * 4096 + n0 + n];
    }
    __syncthreads();
    // xT: 128 n x 64 c
    #pragma unroll
    for (int i = 0; i < 4; ++i) {
        int slot = i * 256 + t;
        int n = slot >> 3, c0 = (slot & 7) * 8;
        bf16 tmp[8];
        #pragma unroll
        for (int j = 0; j < 8; ++j) tmp[j] = (bf16)tile[n * 65 + c0 + j];
        *(bf16x8*)(xT + ((size_t)b * 4096 + n0 + n) * 64 + c0) = *(bf16x8*)tmp;
    }
    // pooled: 32 wp x 64 c
    {
        int wp = t & 31, c0 = (t >> 5) * 8;
        bf16 tmp[8];
        #pragma unroll
        for (int j = 0; j < 8; ++j) {
            float a = tile[(2 * wp) * 65 + c0 + j] + tile[(2 * wp + 1) * 65 + c0 + j]
                    + tile[(64 + 2 * wp) * 65 + c0 + j] + tile[(64 + 2 * wp + 1) * 65 + c0 + j];
            tmp[j] = (bf16)(0.25f * a);
        }
        *(bf16x8*)(xpT + ((size_t)b * 1024 + h2 * 32 + wp) * 64 + c0) = *(bf16x8*)tmp;
    }
}

// ---------------------------------------------------------------------------
// MFMA 1x1-conv, 4 waves/block, each wave one 64o x 64n tile.
//   XT: (B,N,64) bf16.  tr=1 -> Y (B,N,64); tr=0 -> Y (B,64,N).
// grid = (N/256, B, nz).
// ---------------------------------------------------------------------------
__global__ __launch_bounds__(256) void proj_mfma_kernel(
    const bf16* __restrict__ XT, int N,
    const float* __restrict__ W0, const float* __restrict__ B0, bf16* __restrict__ Y0, int t0,
    const float* __restrict__ W1, const float* __restrict__ B1, bf16* __restrict__ Y1, int t1,
    const float* __restrict__ W2, const float* __restrict__ B2, bf16* __restrict__ Y2, int t2)
{
    const int lane = threadIdx.x & 63;
    const int w    = threadIdx.x >> 6;
    const int c16 = lane & 15, q4 = lane >> 4;
    const int n0 = (blockIdx.x * 4 + w) * 64;
    const int b  = blockIdx.y;
    const int z  = blockIdx.z;
    const float* W  = (z == 0) ? W0 : (z == 1) ? W1 : W2;
    const float* Bs = (z == 0) ? B0 : (z == 1) ? B1 : B2;
    bf16*        Y  = (z == 0) ? Y0 : (z == 1) ? Y1 : Y2;
    const int    tr = (z == 0) ? t0 : (z == 1) ? t1 : t2;

    bf16x8 wa[4][2];
    #pragma unroll
    for (int to = 0; to < 4; ++to)
        #pragma unroll
        for (int h = 0; h < 2; ++h) {
            const float* wp = W + (16 * to + c16) * 64 + q4 * 8 + 32 * h;
            float4 f0 = *(const float4*)wp;
            float4 f1 = *(const float4*)(wp + 4);
            bf16 tmp[8] = {(bf16)f0.x, (bf16)f0.y, (bf16)f0.z, (bf16)f0.w,
                           (bf16)f1.x, (bf16)f1.y, (bf16)f1.z, (bf16)f1.w};
            wa[to][h] = *(bf16x8*)tmp;
        }

    f32x4 acc[4][4];
    #pragma unroll
    for (int to = 0; to < 4; ++to)
        #pragma unroll
        for (int tn = 0; tn < 4; ++tn) acc[to][tn] = (f32x4){0.f, 0.f, 0.f, 0.f};

    #pragma unroll
    for (int tn = 0; tn < 4; ++tn) {
        const bf16* xrow = XT + ((size_t)b * N + n0 + 16 * tn + c16) * 64 + q4 * 8;
        bf16x8 xb0 = *(const bf16x8*)xrow;
        bf16x8 xb1 = *(const bf16x8*)(xrow + 32);
        #pragma unroll
        for (int to = 0; to < 4; ++to) {
            acc[to][tn] = __builtin_amdgcn_mfma_f32_16x16x32_bf16(wa[to][0], xb0, acc[to][tn], 0, 0, 0);
            acc[to][tn] = __builtin_amdgcn_mfma_f32_16x16x32_bf16(wa[to][1], xb1, acc[to][tn], 0, 0, 0);
        }
    }

    #pragma unroll
    for (int to = 0; to < 4; ++to) {
        float4 b4 = *(const float4*)(Bs + 16 * to + q4 * 4);
        float bias[4] = {b4.x, b4.y, b4.z, b4.w};
        #pragma unroll
        for (int tn = 0; tn < 4; ++tn) {
            if (tr) {
                bf16 yv[4];
                #pragma unroll
                for (int r = 0; r < 4; ++r) yv[r] = (bf16)(acc[to][tn][r] + bias[r]);
                *(bf16x4*)(Y + ((size_t)b * N + n0 + 16 * tn + c16) * 64 + 16 * to + q4 * 4) = *(bf16x4*)yv;
            } else {
                #pragma unroll
                for (int r = 0; r < 4; ++r)
                    Y[((size_t)b * 64 + 16 * to + q4 * 4 + r) * N + n0 + 16 * tn + c16] =
                        (bf16)(acc[to][tn][r] + bias[r]);
            }
        }
    }
}

// ---------------------------------------------------------------------------
// Flash, S^T/O^T form. 4 waves/block (independent 16-query blocks), no LDS.
//   Qt: (B,NQ,64), Kt: (B,L,64), Vn: (B,64,L), all bf16.
//   sv[t][r] = S^T[m=16t+4q+r][n=c16];  O[g][r] = O^T[c=16g+4q+r][n=c16].
//   PLAYOUT=1: Opart (B,S,NQ,64) row-major.  PLAYOUT=0: (B,S,64,NQ).
// ---------------------------------------------------------------------------
template<int NSPLIT, int PLAYOUT>
__global__ __launch_bounds__(256) void flash_kernel(
    const bf16* __restrict__ Qt, const bf16* __restrict__ Kt,
    const bf16* __restrict__ Vn, int NQ, int L,
    float* __restrict__ Opart, float* __restrict__ Mbuf, float* __restrict__ Lbuf)
{
    const int lane = threadIdx.x & 63;
    const int w    = threadIdx.x >> 6;
    const int c16  = lane & 15;
    const int q4   = lane >> 4;
    const int b    = blockIdx.y;
    const int n0   = (blockIdx.x * 4 + w) * 16;
    const int s    = blockIdx.z;
    const int SL   = L / NSPLIT;
    const int k0   = s * SL, k1 = k0 + SL;

    const int lane_a = c16 | (((2 * q4) & 3) << 4);
    const int lane_b = c16 | (((2 * q4 + 1) & 3) << 4);
    const bool hi = (q4 >= 2);

    // Q B-frags (col n = n0+c16)
    const bf16* qrow = Qt + ((size_t)b * NQ + n0 + c16) * 64 + q4 * 8;
    bf16x8 bq0 = *(const bf16x8*)(qrow);
    bf16x8 bq1 = *(const bf16x8*)(qrow + 32);

    f32x4 O[4];
    #pragma unroll
    for (int g = 0; g < 4; ++g) O[g] = (f32x4){0.f, 0.f, 0.f, 0.f};
    float m_run = -INFINITY, l_run = 0.f;

    const bf16* Kb = Kt + (size_t)b * L * 64;
    const bf16* Vb = Vn + (size_t)b * 64 * L;

    for (int kt = k0; kt < k1; kt += 64) {
        // ---- S^T tiles: A = K-frags, B = Q-frags ----
        f32x4 sv[4];
        #pragma unroll
        for (int t = 0; t < 4; ++t) {
            const bf16* krow = Kb + ((size_t)(kt + 16 * t + c16)) * 64 + q4 * 8;
            bf16x8 ak0 = *(const bf16x8*)(krow);
            bf16x8 ak1 = *(const bf16x8*)(krow + 32);
            f32x4 z = (f32x4){0.f, 0.f, 0.f, 0.f};
            z = __builtin_amdgcn_mfma_f32_16x16x32_bf16(ak0, bq0, z, 0, 0, 0);
            sv[t] = __builtin_amdgcn_mfma_f32_16x16x32_bf16(ak1, bq1, z, 0, 0, 0);
        }

        // ---- per-query (per-lane) softmax stats: in-lane + 2 shuffles ----
        float mx = sv[0][0];
        #pragma unroll
        for (int t = 0; t < 4; ++t)
            #pragma unroll
            for (int r = 0; r < 4; ++r) mx = fmaxf(mx, sv[t][r]);
        mx = fmaxf(mx, __shfl_xor(mx, 16));
        mx = fmaxf(mx, __shfl_xor(mx, 32));
        float nm = fmaxf(m_run, mx);
        float alpha = __expf(m_run - nm);
        m_run = nm;

        float ls = 0.f;
        #pragma unroll
        for (int t = 0; t < 4; ++t)
            #pragma unroll
            for (int r = 0; r < 4; ++r) {
                float p = __expf(sv[t][r] - nm);
                sv[t][r] = p;
                ls += p;
            }
        ls += __shfl_xor(ls, 16);
        ls += __shfl_xor(ls, 32);
        l_run = l_run * alpha + ls;
        #pragma unroll
        for (int g = 0; g < 4; ++g)
            #pragma unroll
            for (int r = 0; r < 4; ++r) O[g][r] *= alpha;

        // ---- pack P to bf16 pairs ----
        unsigned int pk[4][2];
        #pragma unroll
        for (int t = 0; t < 4; ++t) {
            pk[t][0] = pack_bf16(sv[t][0], sv[t][1]);
            pk[t][1] = pack_bf16(sv[t][2], sv[t][3]);
        }

        // ---- P B-frags via cross-quad shuffles, then PV ----
        #pragma unroll
        for (int h = 0; h < 2; ++h) {
            unsigned xa0 = __shfl((int)pk[2 * h][0], lane_a);
            unsigned xa1 = __shfl((int)pk[2 * h][1], lane_a);
            unsigned ya0 = __shfl((int)pk[2 * h + 1][0], lane_a);
            unsigned ya1 = __shfl((int)pk[2 * h + 1][1], lane_a);
            unsigned xb0 = __shfl((int)pk[2 * h][0], lane_b);
            unsigned xb1 = __shfl((int)pk[2 * h][1], lane_b);
            unsigned yb0 = __shfl((int)pk[2 * h + 1][0], lane_b);
            unsigned yb1 = __shfl((int)pk[2 * h + 1][1], lane_b);
            PackU pu;
            pu.u[0] = hi ? ya0 : xa0;
            pu.u[1] = hi ? ya1 : xa1;
            pu.u[2] = hi ? yb0 : xb0;
            pu.u[3] = hi ? yb1 : xb1;
            bf16x8 pf = pu.v;
            #pragma unroll
            for (int g = 0; g < 4; ++g) {
                const bf16* vrow = Vb + ((size_t)(16 * g + c16)) * L + kt + 32 * h + q4 * 8;
                bf16x8 av = *(const bf16x8*)vrow;
                O[g] = __builtin_amdgcn_mfma_f32_16x16x32_bf16(av, pf, O[g], 0, 0, 0);
            }
        }
    }

    if (PLAYOUT == 1) {
        float* dst = Opart + ((size_t)(b * NSPLIT + s) * NQ + n0 + c16) * 64 + q4 * 4;
        #pragma unroll
        for (int g = 0; g < 4; ++g) *(f32x4*)(dst + 16 * g) = O[g];
    } else {
        #pragma unroll
        for (int g = 0; g < 4; ++g)
            #pragma unroll
            for (int r = 0; r < 4; ++r)
                Opart[((size_t)(b * NSPLIT + s) * 64 + 16 * g + q4 * 4 + r) * NQ + n0 + c16] = O[g][r];
    }
    if (lane < 16) {
        Mbuf[(b * NSPLIT + s) * NQ + n0 + lane] = m_run;
        Lbuf[(b * NSPLIT + s) * NQ + n0 + lane] = l_run;
    }
}

// ---------------------------------------------------------------------------
// Combine stage-1 partials (8 splits, row-major) -> out1T (B,1024,64) bf16.
// ---------------------------------------------------------------------------
__global__ __launch_bounds__(256) void combine1_kernel(
    const float* __restrict__ Opart, const float* __restrict__ Mbuf,
    const float* __restrict__ Lbuf, bf16* __restrict__ out1T)
{
    int idx = blockIdx.x * 256 + threadIdx.x;   // 8*1024*64
    int c = idx & 63;
    int m = (idx >> 6) & 1023;
    int b = idx >> 16;
    float ms[8], ls[8];
    #pragma unroll
    for (int s = 0; s < 8; ++s) {
        ms[s] = Mbuf[(b * 8 + s) * 1024 + m];
        ls[s] = Lbuf[(b * 8 + s) * 1024 + m];
    }
    float M = ms[0];
    #pragma unroll
    for (int s = 1; s < 8; ++s) M = fmaxf(M, ms[s]);
    float lt = 0.f, acc = 0.f;
    #pragma unroll
    for (int s = 0; s < 8; ++s) {
        float wgt = __expf(ms[s] - M);
        lt += ls[s] * wgt;
        acc += Opart[((size_t)(b * 8 + s) * 1024 + m) * 64 + c] * wgt;
    }
    out1T[idx] = (bf16)(acc / lt);
}

// ---------------------------------------------------------------------------
// Combine stage-2 partials (2 splits, channel-major) + gamma + residual.
// ---------------------------------------------------------------------------
__global__ __launch_bounds__(256) void combine2_kernel(
    const float* __restrict__ Opart, const float* __restrict__ Mbuf,
    const float* __restrict__ Lbuf, const float* __restrict__ x,
    const float* __restrict__ gamma_p, float* __restrict__ out)
{
    int idx = blockIdx.x * 256 + threadIdx.x;   // 8*64*4096
    int n = idx & 4095;
    int b = idx >> 18;
    float m0 = Mbuf[(b * 2 + 0) * 4096 + n], m1 = Mbuf[(b * 2 + 1) * 4096 + n];
    float l0 = Lbuf[(b * 2 + 0) * 4096 + n], l1 = Lbuf[(b * 2 + 1) * 4096 + n];
    float M = fmaxf(m0, m1);
    float w0 = __expf(m0 - M), w1 = __expf(m1 - M);
    float lt = l0 * w0 + l1 * w1;
    int c = (idx >> 12) & 63;
    float acc = Opart[((size_t)(b * 2 + 0) * 64 + c) * 4096 + n] * w0
              + Opart[((size_t)(b * 2 + 1) * 64 + c) * 4096 + n] * w1;
    out[idx] = gamma_p[0] * (acc / lt) + x[idx];
}

// ---------------------------------------------------------------------------
extern "C" void kernel_launch(void* const* d_in, const int* in_sizes, int n_in,
                              void* d_out, int out_size, void* d_ws, size_t ws_size,
                              hipStream_t stream) {
    const float* x    = (const float*)d_in[0];
    const float* w_q  = (const float*)d_in[1];
    const float* b_q  = (const float*)d_in[2];
    const float* w_K  = (const float*)d_in[3];
    const float* b_K  = (const float*)d_in[4];
    const float* w_V  = (const float*)d_in[5];
    const float* b_V  = (const float*)d_in[6];
    const float* w_Q  = (const float*)d_in[7];
    const float* b_Q  = (const float*)d_in[8];
    const float* w_k  = (const float*)d_in[9];
    const float* b_k  = (const float*)d_in[10];
    const float* w_v  = (const float*)d_in[11];
    const float* b_v  = (const float*)d_in[12];
    const float* gamma = (const float*)d_in[13];
    float* out = (float*)d_out;

    char* ws = (char*)d_ws;
    bf16*  xT    = (bf16*)ws;   ws += (size_t)8 * 4096 * 64 * 2;       // 4MB
    bf16*  Kt    = (bf16*)ws;   ws += (size_t)8 * 4096 * 64 * 2;       // 4MB
    bf16*  Qt    = (bf16*)ws;   ws += (size_t)8 * 4096 * 64 * 2;       // 4MB
    bf16*  Vf    = (bf16*)ws;   ws += (size_t)8 * 4096 * 64 * 2;       // 4MB
    bf16*  xpT   = (bf16*)ws;   ws += (size_t)8 * 1024 * 64 * 2;       // 1MB
    bf16*  qpt   = (bf16*)ws;   ws += (size_t)8 * 1024 * 64 * 2;       // 1MB
    bf16*  out1T = (bf16*)ws;   ws += (size_t)8 * 1024 * 64 * 2;       // 1MB
    bf16*  kpt   = (bf16*)ws;   ws += (size_t)8 * 1024 * 64 * 2;       // 1MB
    bf16*  vp    = (bf16*)ws;   ws += (size_t)8 * 64 * 1024 * 2;       // 1MB
    float* Opart = (float*)ws;  ws += (size_t)8 * 8 * 1024 * 64 * 4;   // 16MB (shared)
    float* Mb    = (float*)ws;  ws += (size_t)8 * 8 * 1024 * 4;        // 256KB (shared)
    float* Lb    = (float*)ws;  ws += (size_t)8 * 8 * 1024 * 4;        // 256KB (shared)

    // 1) transpose-cast + pool
    transpool_kernel<<<dim3(32, 8), 256, 0, stream>>>(x, xT, xpT);

    // 2) K,Q (transposed) and V (normal) projections of xT
    proj_mfma_kernel<<<dim3(16, 8, 3), 256, 0, stream>>>(
        xT, 4096, w_K, b_K, Kt, 1, w_Q, b_Q, Qt, 1, w_V, b_V, Vf, 0);

    // 3) pooled-query projection (transposed)
    proj_mfma_kernel<<<dim3(4, 8, 1), 256, 0, stream>>>(
        xpT, 1024, w_q, b_q, qpt, 1,
        nullptr, nullptr, nullptr, 0, nullptr, nullptr, nullptr, 0);

    // 4) stage-1 flash: qpt (1024 q) vs Kt/Vf (L=4096), split x8
    flash_kernel<8, 1><<<dim3(16, 8, 8), 256, 0, stream>>>(
        qpt, Kt, Vf, 1024, 4096, Opart, Mb, Lb);

    // 5) combine -> out1T
    combine1_kernel<<<2048, 256, 0, stream>>>(Opart, Mb, Lb, out1T);

    // 6) k (transposed) and v (normal) projections of out1T
    proj_mfma_kernel<<<dim3(4, 8, 2), 256, 0, stream>>>(
        out1T, 1024, w_k, b_k, kpt, 1, w_v, b_v, vp, 0,
        nullptr, nullptr, nullptr, 0);

    // 7) stage-2 flash: Qt (4096 q) vs kpt/vp (L=1024), split x2
    flash_kernel<2, 0><<<dim3(64, 8, 2), 256, 0, stream>>>(
        Qt, kpt, vp, 4096, 1024, Opart, Mb, Lb);

    // 8) combine + gamma + residual
    combine2_kernel<<<8192, 256, 0, stream>>>(Opart, Mb, Lb, x, gamma, out);
}

// Round 5
// 177.017 us; speedup vs baseline: 1.4104x; 1.4104x over previous
//
#include <hip/hip_runtime.h>
#include <math.h>

// B=8, C=64, H=W=64, N=4096, N4=1024. bf16 MFMA, fp32 accumulate.
// Flash: S^T/O^T form, per-lane softmax, shuffle P-transform; K/V tiles
// staged in LDS (padded stride 72) shared by the 4 waves of a block,
// double-buffered, one barrier per tile.

typedef __bf16 bf16;
typedef __attribute__((ext_vector_type(2))) __bf16 bf16x2;
typedef __attribute__((ext_vector_type(4))) __bf16 bf16x4;
typedef __attribute__((ext_vector_type(8))) __bf16 bf16x8;
typedef __attribute__((ext_vector_type(4))) float f32x4;

union Pack2 { unsigned int u; bf16x2 v; };
union PackU { unsigned int u[4]; bf16x8 v; };

__device__ inline unsigned int pack_bf16(float a, float b) {
    Pack2 p; p.v = (bf16x2){(bf16)a, (bf16)b}; return p.u;
}

// ---------------------------------------------------------------------------
// Fused transpose-cast + 2x2 pool:
//   x (B,64,4096) fp32 -> xT (B,4096,64) bf16, xpT (B,1024,64) bf16.
// ---------------------------------------------------------------------------
__global__ __launch_bounds__(256) void transpool_kernel(const float* __restrict__ x,
                                                        bf16* __restrict__ xT,
                                                        bf16* __restrict__ xpT) {
    __shared__ float tile[128 * 65];
    const int t  = threadIdx.x;
    const int h2 = blockIdx.x;
    const int b  = blockIdx.y;
    const int n0 = h2 * 128;
    #pragma unroll
    for (int i = 0; i < 32; ++i) {
        int lin = i * 256 + t;
        int n = lin & 127, c = lin >> 7;
        tile[n * 65 + c] = x[((size_t)b * 64 + c) * 4096 + n0 + n];
    }
    __syncthreads();
    #pragma unroll
    for (int i = 0; i < 4; ++i) {
        int slot = i * 256 + t;
        int n = slot >> 3, c0 = (slot & 7) * 8;
        bf16 tmp[8];
        #pragma unroll
        for (int j = 0; j < 8; ++j) tmp[j] = (bf16)tile[n * 65 + c0 + j];
        *(bf16x8*)(xT + ((size_t)b * 4096 + n0 + n) * 64 + c0) = *(bf16x8*)tmp;
    }
    {
        int wp = t & 31, c0 = (t >> 5) * 8;
        bf16 tmp[8];
        #pragma unroll
        for (int j = 0; j < 8; ++j) {
            float a = tile[(2 * wp) * 65 + c0 + j] + tile[(2 * wp + 1) * 65 + c0 + j]
                    + tile[(64 + 2 * wp) * 65 + c0 + j] + tile[(64 + 2 * wp + 1) * 65 + c0 + j];
            tmp[j] = (bf16)(0.25f * a);
        }
        *(bf16x8*)(xpT + ((size_t)b * 1024 + h2 * 32 + wp) * 64 + c0) = *(bf16x8*)tmp;
    }
}

// ---------------------------------------------------------------------------
// MFMA 1x1-conv, 4 waves/block, each wave one 64o x 64n tile.
// ---------------------------------------------------------------------------
__global__ __launch_bounds__(256) void proj_mfma_kernel(
    const bf16* __restrict__ XT, int N,
    const float* __restrict__ W0, const float* __restrict__ B0, bf16* __restrict__ Y0, int t0,
    const float* __restrict__ W1, const float* __restrict__ B1, bf16* __restrict__ Y1, int t1,
    const float* __restrict__ W2, const float* __restrict__ B2, bf16* __restrict__ Y2, int t2)
{
    const int lane = threadIdx.x & 63;
    const int w    = threadIdx.x >> 6;
    const int c16 = lane & 15, q4 = lane >> 4;
    const int n0 = (blockIdx.x * 4 + w) * 64;
    const int b  = blockIdx.y;
    const int z  = blockIdx.z;
    const float* W  = (z == 0) ? W0 : (z == 1) ? W1 : W2;
    const float* Bs = (z == 0) ? B0 : (z == 1) ? B1 : B2;
    bf16*        Y  = (z == 0) ? Y0 : (z == 1) ? Y1 : Y2;
    const int    tr = (z == 0) ? t0 : (z == 1) ? t1 : t2;

    bf16x8 wa[4][2];
    #pragma unroll
    for (int to = 0; to < 4; ++to)
        #pragma unroll
        for (int h = 0; h < 2; ++h) {
            const float* wp = W + (16 * to + c16) * 64 + q4 * 8 + 32 * h;
            float4 f0 = *(const float4*)wp;
            float4 f1 = *(const float4*)(wp + 4);
            bf16 tmp[8] = {(bf16)f0.x, (bf16)f0.y, (bf16)f0.z, (bf16)f0.w,
                           (bf16)f1.x, (bf16)f1.y, (bf16)f1.z, (bf16)f1.w};
            wa[to][h] = *(bf16x8*)tmp;
        }

    f32x4 acc[4][4];
    #pragma unroll
    for (int to = 0; to < 4; ++to)
        #pragma unroll
        for (int tn = 0; tn < 4; ++tn) acc[to][tn] = (f32x4){0.f, 0.f, 0.f, 0.f};

    #pragma unroll
    for (int tn = 0; tn < 4; ++tn) {
        const bf16* xrow = XT + ((size_t)b * N + n0 + 16 * tn + c16) * 64 + q4 * 8;
        bf16x8 xb0 = *(const bf16x8*)xrow;
        bf16x8 xb1 = *(const bf16x8*)(xrow + 32);
        #pragma unroll
        for (int to = 0; to < 4; ++to) {
            acc[to][tn] = __builtin_amdgcn_mfma_f32_16x16x32_bf16(wa[to][0], xb0, acc[to][tn], 0, 0, 0);
            acc[to][tn] = __builtin_amdgcn_mfma_f32_16x16x32_bf16(wa[to][1], xb1, acc[to][tn], 0, 0, 0);
        }
    }

    #pragma unroll
    for (int to = 0; to < 4; ++to) {
        float4 b4 = *(const float4*)(Bs + 16 * to + q4 * 4);
        float bias[4] = {b4.x, b4.y, b4.z, b4.w};
        #pragma unroll
        for (int tn = 0; tn < 4; ++tn) {
            if (tr) {
                bf16 yv[4];
                #pragma unroll
                for (int r = 0; r < 4; ++r) yv[r] = (bf16)(acc[to][tn][r] + bias[r]);
                *(bf16x4*)(Y + ((size_t)b * N + n0 + 16 * tn + c16) * 64 + 16 * to + q4 * 4) = *(bf16x4*)yv;
            } else {
                #pragma unroll
                for (int r = 0; r < 4; ++r)
                    Y[((size_t)b * 64 + 16 * to + q4 * 4 + r) * N + n0 + 16 * tn + c16] =
                        (bf16)(acc[to][tn][r] + bias[r]);
            }
        }
    }
}

// ---------------------------------------------------------------------------
// Flash, S^T/O^T form with LDS-shared K/V tiles.
//   Qt: (B,NQ,64), Kt: (B,L,64), Vn: (B,64,L), bf16.
//   Block = 4 waves = 64 queries; K/V 64x64 tiles staged in LDS (stride 72,
//   bank-balanced), double-buffered, 1 barrier/tile.
// ---------------------------------------------------------------------------
template<int NSPLIT, int PLAYOUT>
__global__ __launch_bounds__(256) void flash_kernel(
    const bf16* __restrict__ Qt, const bf16* __restrict__ Kt,
    const bf16* __restrict__ Vn, int NQ, int L,
    float* __restrict__ Opart, float* __restrict__ Mbuf, float* __restrict__ Lbuf)
{
    const int tid  = threadIdx.x;
    const int lane = tid & 63;
    const int w    = tid >> 6;
    const int c16  = lane & 15;
    const int q4   = lane >> 4;
    const int b    = blockIdx.y;
    const int n0   = blockIdx.x * 64 + w * 16;
    const int s    = blockIdx.z;
    const int SL   = L / NSPLIT;
    const int k0   = s * SL;
    const int ntiles = SL / 64;

    __shared__ __align__(16) bf16 Ks[2][64 * 72];
    __shared__ __align__(16) bf16 Vs[2][64 * 72];

    // staging coords: thread -> (row 0..63, 32B chunk)
    const int srow = tid >> 2;
    const int scol = (tid & 3) * 16;

    const int lane_a = c16 | (((2 * q4) & 3) << 4);
    const int lane_b = c16 | (((2 * q4 + 1) & 3) << 4);
    const bool hi = (q4 >= 2);

    const bf16* Kb = Kt + (size_t)b * L * 64;
    const bf16* Vb = Vn + (size_t)b * 64 * L;

    // Q B-frags
    const bf16* qrow = Qt + ((size_t)b * NQ + n0 + c16) * 64 + q4 * 8;
    bf16x8 bq0 = *(const bf16x8*)(qrow);
    bf16x8 bq1 = *(const bf16x8*)(qrow + 32);

    f32x4 O[4];
    #pragma unroll
    for (int g = 0; g < 4; ++g) O[g] = (f32x4){0.f, 0.f, 0.f, 0.f};
    float m_run = -INFINITY, l_run = 0.f;

    // ---- stage tile 0 ----
    {
        const bf16* kg = Kb + ((size_t)(k0 + srow)) * 64 + scol;
        *(bf16x8*)&Ks[0][srow * 72 + scol]     = *(const bf16x8*)kg;
        *(bf16x8*)&Ks[0][srow * 72 + scol + 8] = *(const bf16x8*)(kg + 8);
        const bf16* vg = Vb + (size_t)srow * L + k0 + scol;
        *(bf16x8*)&Vs[0][srow * 72 + scol]     = *(const bf16x8*)vg;
        *(bf16x8*)&Vs[0][srow * 72 + scol + 8] = *(const bf16x8*)(vg + 8);
    }
    __syncthreads();

    for (int it = 0; it < ntiles; ++it) {
        const int buf = it & 1;
        // ---- prefetch next tile into the other buffer ----
        if (it + 1 < ntiles) {
            const int kn = k0 + (it + 1) * 64;
            const bf16* kg = Kb + ((size_t)(kn + srow)) * 64 + scol;
            *(bf16x8*)&Ks[buf ^ 1][srow * 72 + scol]     = *(const bf16x8*)kg;
            *(bf16x8*)&Ks[buf ^ 1][srow * 72 + scol + 8] = *(const bf16x8*)(kg + 8);
            const bf16* vg = Vb + (size_t)srow * L + kn + scol;
            *(bf16x8*)&Vs[buf ^ 1][srow * 72 + scol]     = *(const bf16x8*)vg;
            *(bf16x8*)&Vs[buf ^ 1][srow * 72 + scol + 8] = *(const bf16x8*)(vg + 8);
        }

        // ---- S^T tiles: A = K-frags (LDS), B = Q-frags ----
        f32x4 sv[4];
        #pragma unroll
        for (int t = 0; t < 4; ++t) {
            const bf16* krow = &Ks[buf][(16 * t + c16) * 72 + q4 * 8];
            bf16x8 ak0 = *(const bf16x8*)(krow);
            bf16x8 ak1 = *(const bf16x8*)(krow + 32);
            f32x4 z = (f32x4){0.f, 0.f, 0.f, 0.f};
            z = __builtin_amdgcn_mfma_f32_16x16x32_bf16(ak0, bq0, z, 0, 0, 0);
            sv[t] = __builtin_amdgcn_mfma_f32_16x16x32_bf16(ak1, bq1, z, 0, 0, 0);
        }

        // ---- per-lane softmax stats ----
        float mx = sv[0][0];
        #pragma unroll
        for (int t = 0; t < 4; ++t)
            #pragma unroll
            for (int r = 0; r < 4; ++r) mx = fmaxf(mx, sv[t][r]);
        mx = fmaxf(mx, __shfl_xor(mx, 16));
        mx = fmaxf(mx, __shfl_xor(mx, 32));
        float nm = fmaxf(m_run, mx);
        float alpha = __expf(m_run - nm);
        m_run = nm;

        float ls = 0.f;
        #pragma unroll
        for (int t = 0; t < 4; ++t)
            #pragma unroll
            for (int r = 0; r < 4; ++r) {
                float p = __expf(sv[t][r] - nm);
                sv[t][r] = p;
                ls += p;
            }
        ls += __shfl_xor(ls, 16);
        ls += __shfl_xor(ls, 32);
        l_run = l_run * alpha + ls;
        #pragma unroll
        for (int g = 0; g < 4; ++g)
            #pragma unroll
            for (int r = 0; r < 4; ++r) O[g][r] *= alpha;

        // ---- pack P, transform to B-frags via shuffles, PV ----
        unsigned int pk[4][2];
        #pragma unroll
        for (int t = 0; t < 4; ++t) {
            pk[t][0] = pack_bf16(sv[t][0], sv[t][1]);
            pk[t][1] = pack_bf16(sv[t][2], sv[t][3]);
        }
        #pragma unroll
        for (int h = 0; h < 2; ++h) {
            unsigned xa0 = __shfl((int)pk[2 * h][0], lane_a);
            unsigned xa1 = __shfl((int)pk[2 * h][1], lane_a);
            unsigned ya0 = __shfl((int)pk[2 * h + 1][0], lane_a);
            unsigned ya1 = __shfl((int)pk[2 * h + 1][1], lane_a);
            unsigned xb0 = __shfl((int)pk[2 * h][0], lane_b);
            unsigned xb1 = __shfl((int)pk[2 * h][1], lane_b);
            unsigned yb0 = __shfl((int)pk[2 * h + 1][0], lane_b);
            unsigned yb1 = __shfl((int)pk[2 * h + 1][1], lane_b);
            PackU pu;
            pu.u[0] = hi ? ya0 : xa0;
            pu.u[1] = hi ? ya1 : xa1;
            pu.u[2] = hi ? yb0 : xb0;
            pu.u[3] = hi ? yb1 : xb1;
            bf16x8 pf = pu.v;
            #pragma unroll
            for (int g = 0; g < 4; ++g) {
                const bf16* vrow = &Vs[buf][(16 * g + c16) * 72 + 32 * h + q4 * 8];
                bf16x8 av = *(const bf16x8*)vrow;
                O[g] = __builtin_amdgcn_mfma_f32_16x16x32_bf16(av, pf, O[g], 0, 0, 0);
            }
        }
        __syncthreads();
    }

    if (PLAYOUT == 1) {
        float* dst = Opart + ((size_t)(b * NSPLIT + s) * NQ + n0 + c16) * 64 + q4 * 4;
        #pragma unroll
        for (int g = 0; g < 4; ++g) *(f32x4*)(dst + 16 * g) = O[g];
    } else {
        #pragma unroll
        for (int g = 0; g < 4; ++g)
            #pragma unroll
            for (int r = 0; r < 4; ++r)
                Opart[((size_t)(b * NSPLIT + s) * 64 + 16 * g + q4 * 4 + r) * NQ + n0 + c16] = O[g][r];
    }
    if (lane < 16) {
        Mbuf[(b * NSPLIT + s) * NQ + n0 + lane] = m_run;
        Lbuf[(b * NSPLIT + s) * NQ + n0 + lane] = l_run;
    }
}

// ---------------------------------------------------------------------------
// Combine stage-1 partials (8 splits, row-major) -> out1T (B,1024,64) bf16.
// ---------------------------------------------------------------------------
__global__ __launch_bounds__(256) void combine1_kernel(
    const float* __restrict__ Opart, const float* __restrict__ Mbuf,
    const float* __restrict__ Lbuf, bf16* __restrict__ out1T)
{
    int idx = blockIdx.x * 256 + threadIdx.x;
    int c = idx & 63;
    int m = (idx >> 6) & 1023;
    int b = idx >> 16;
    float ms[8], ls[8];
    #pragma unroll
    for (int s = 0; s < 8; ++s) {
        ms[s] = Mbuf[(b * 8 + s) * 1024 + m];
        ls[s] = Lbuf[(b * 8 + s) * 1024 + m];
    }
    float M = ms[0];
    #pragma unroll
    for (int s = 1; s < 8; ++s) M = fmaxf(M, ms[s]);
    float lt = 0.f, acc = 0.f;
    #pragma unroll
    for (int s = 0; s < 8; ++s) {
        float wgt = __expf(ms[s] - M);
        lt += ls[s] * wgt;
        acc += Opart[((size_t)(b * 8 + s) * 1024 + m) * 64 + c] * wgt;
    }
    out1T[idx] = (bf16)(acc / lt);
}

// ---------------------------------------------------------------------------
// Combine stage-2 partials (2 splits, channel-major) + gamma + residual.
// ---------------------------------------------------------------------------
__global__ __launch_bounds__(256) void combine2_kernel(
    const float* __restrict__ Opart, const float* __restrict__ Mbuf,
    const float* __restrict__ Lbuf, const float* __restrict__ x,
    const float* __restrict__ gamma_p, float* __restrict__ out)
{
    int idx = blockIdx.x * 256 + threadIdx.x;
    int n = idx & 4095;
    int b = idx >> 18;
    float m0 = Mbuf[(b * 2 + 0) * 4096 + n], m1 = Mbuf[(b * 2 + 1) * 4096 + n];
    float l0 = Lbuf[(b * 2 + 0) * 4096 + n], l1 = Lbuf[(b * 2 + 1) * 4096 + n];
    float M = fmaxf(m0, m1);
    float w0 = __expf(m0 - M), w1 = __expf(m1 - M);
    float lt = l0 * w0 + l1 * w1;
    int c = (idx >> 12) & 63;
    float acc = Opart[((size_t)(b * 2 + 0) * 64 + c) * 4096 + n] * w0
              + Opart[((size_t)(b * 2 + 1) * 64 + c) * 4096 + n] * w1;
    out[idx] = gamma_p[0] * (acc / lt) + x[idx];
}

// ---------------------------------------------------------------------------
extern "C" void kernel_launch(void* const* d_in, const int* in_sizes, int n_in,
                              void* d_out, int out_size, void* d_ws, size_t ws_size,
                              hipStream_t stream) {
    const float* x    = (const float*)d_in[0];
    const float* w_q  = (const float*)d_in[1];
    const float* b_q  = (const float*)d_in[2];
    const float* w_K  = (const float*)d_in[3];
    const float* b_K  = (const float*)d_in[4];
    const float* w_V  = (const float*)d_in[5];
    const float* b_V  = (const float*)d_in[6];
    const float* w_Q  = (const float*)d_in[7];
    const float* b_Q  = (const float*)d_in[8];
    const float* w_k  = (const float*)d_in[9];
    const float* b_k  = (const float*)d_in[10];
    const float* w_v  = (const float*)d_in[11];
    const float* b_v  = (const float*)d_in[12];
    const float* gamma = (const float*)d_in[13];
    float* out = (float*)d_out;

    char* ws = (char*)d_ws;
    bf16*  xT    = (bf16*)ws;   ws += (size_t)8 * 4096 * 64 * 2;
    bf16*  Kt    = (bf16*)ws;   ws += (size_t)8 * 4096 * 64 * 2;
    bf16*  Qt    = (bf16*)ws;   ws += (size_t)8 * 4096 * 64 * 2;
    bf16*  Vf    = (bf16*)ws;   ws += (size_t)8 * 4096 * 64 * 2;
    bf16*  xpT   = (bf16*)ws;   ws += (size_t)8 * 1024 * 64 * 2;
    bf16*  qpt   = (bf16*)ws;   ws += (size_t)8 * 1024 * 64 * 2;
    bf16*  out1T = (bf16*)ws;   ws += (size_t)8 * 1024 * 64 * 2;
    bf16*  kpt   = (bf16*)ws;   ws += (size_t)8 * 1024 * 64 * 2;
    bf16*  vp    = (bf16*)ws;   ws += (size_t)8 * 64 * 1024 * 2;
    float* Opart = (float*)ws;  ws += (size_t)8 * 8 * 1024 * 64 * 4;
    float* Mb    = (float*)ws;  ws += (size_t)8 * 8 * 1024 * 4;
    float* Lb    = (float*)ws;  ws += (size_t)8 * 8 * 1024 * 4;

    // 1) transpose-cast + pool
    transpool_kernel<<<dim3(32, 8), 256, 0, stream>>>(x, xT, xpT);

    // 2) K,Q (transposed) and V (normal) projections of xT
    proj_mfma_kernel<<<dim3(16, 8, 3), 256, 0, stream>>>(
        xT, 4096, w_K, b_K, Kt, 1, w_Q, b_Q, Qt, 1, w_V, b_V, Vf, 0);

    // 3) pooled-query projection (transposed)
    proj_mfma_kernel<<<dim3(4, 8, 1), 256, 0, stream>>>(
        xpT, 1024, w_q, b_q, qpt, 1,
        nullptr, nullptr, nullptr, 0, nullptr, nullptr, nullptr, 0);

    // 4) stage-1 flash: qpt (1024 q) vs Kt/Vf (L=4096), split x8
    flash_kernel<8, 1><<<dim3(16, 8, 8), 256, 0, stream>>>(
        qpt, Kt, Vf, 1024, 4096, Opart, Mb, Lb);

    // 5) combine -> out1T
    combine1_kernel<<<2048, 256, 0, stream>>>(Opart, Mb, Lb, out1T);

    // 6) k (transposed) and v (normal) projections of out1T
    proj_mfma_kernel<<<dim3(4, 8, 2), 256, 0, stream>>>(
        out1T, 1024, w_k, b_k, kpt, 1, w_v, b_v, vp, 0,
        nullptr, nullptr, nullptr, 0);

    // 7) stage-2 flash: Qt (4096 q) vs kpt/vp (L=1024), split x2
    flash_kernel<2, 0><<<dim3(64, 8, 2), 256, 0, stream>>>(
        Qt, kpt, vp, 4096, 1024, Opart, Mb, Lb);

    // 8) combine + gamma + residual
    combine2_kernel<<<8192, 256, 0, stream>>>(Opart, Mb, Lb, x, gamma, out);
}

// Round 6
// 163.506 us; speedup vs baseline: 1.5270x; 1.0826x over previous
//
#include <hip/hip_runtime.h>
#include <math.h>

// B=8, C=64, H=W=64, N=4096, N4=1024. bf16 MFMA, fp32 accumulate.
// Flash: S^T/O^T form, 32 queries/wave (128/block), K/V tiles LDS-shared
// across 4 waves (stride 72 = uniform bank spread), double-buffered;
// P-transform through a private per-wave LDS buffer (no barrier).

typedef __bf16 bf16;
typedef __attribute__((ext_vector_type(4))) __bf16 bf16x4;
typedef __attribute__((ext_vector_type(8))) __bf16 bf16x8;
typedef __attribute__((ext_vector_type(4))) float f32x4;

// ---------------------------------------------------------------------------
// Fused transpose-cast + 2x2 pool:
//   x (B,64,4096) fp32 -> xT (B,4096,64) bf16, xpT (B,1024,64) bf16.
// ---------------------------------------------------------------------------
__global__ __launch_bounds__(256) void transpool_kernel(const float* __restrict__ x,
                                                        bf16* __restrict__ xT,
                                                        bf16* __restrict__ xpT) {
    __shared__ float tile[128 * 65];
    const int t  = threadIdx.x;
    const int h2 = blockIdx.x;
    const int b  = blockIdx.y;
    const int n0 = h2 * 128;
    #pragma unroll
    for (int i = 0; i < 32; ++i) {
        int lin = i * 256 + t;
        int n = lin & 127, c = lin >> 7;
        tile[n * 65 + c] = x[((size_t)b * 64 + c) * 4096 + n0 + n];
    }
    __syncthreads();
    #pragma unroll
    for (int i = 0; i < 4; ++i) {
        int slot = i * 256 + t;
        int n = slot >> 3, c0 = (slot & 7) * 8;
        bf16 tmp[8];
        #pragma unroll
        for (int j = 0; j < 8; ++j) tmp[j] = (bf16)tile[n * 65 + c0 + j];
        *(bf16x8*)(xT + ((size_t)b * 4096 + n0 + n) * 64 + c0) = *(bf16x8*)tmp;
    }
    {
        int wp = t & 31, c0 = (t >> 5) * 8;
        bf16 tmp[8];
        #pragma unroll
        for (int j = 0; j < 8; ++j) {
            float a = tile[(2 * wp) * 65 + c0 + j] + tile[(2 * wp + 1) * 65 + c0 + j]
                    + tile[(64 + 2 * wp) * 65 + c0 + j] + tile[(64 + 2 * wp + 1) * 65 + c0 + j];
            tmp[j] = (bf16)(0.25f * a);
        }
        *(bf16x8*)(xpT + ((size_t)b * 1024 + h2 * 32 + wp) * 64 + c0) = *(bf16x8*)tmp;
    }
}

// ---------------------------------------------------------------------------
// All four projections in one launch. z=0:K(tr), z=1:Q(tr), z=2:V(no-tr),
// z=3:q-pooled(tr, reads xpT, only 4 x-blocks active).
// Block = 4 waves, each wave one 64o x 64n MFMA tile.
// ---------------------------------------------------------------------------
__global__ __launch_bounds__(256) void proj_all_kernel(
    const bf16* __restrict__ xT, const bf16* __restrict__ xpT,
    const float* __restrict__ w_K, const float* __restrict__ b_K, bf16* __restrict__ Kt,
    const float* __restrict__ w_Q, const float* __restrict__ b_Q, bf16* __restrict__ Qt,
    const float* __restrict__ w_V, const float* __restrict__ b_V, bf16* __restrict__ Vf,
    const float* __restrict__ w_q, const float* __restrict__ b_q, bf16* __restrict__ qpt)
{
    const int z = blockIdx.z;
    if (z == 3 && blockIdx.x >= 4) return;
    const bf16*  XT = (z == 3) ? xpT : xT;
    const int    N  = (z == 3) ? 1024 : 4096;
    const float* W  = (z == 0) ? w_K : (z == 1) ? w_Q : (z == 2) ? w_V : w_q;
    const float* Bs = (z == 0) ? b_K : (z == 1) ? b_Q : (z == 2) ? b_V : b_q;
    bf16*        Y  = (z == 0) ? Kt  : (z == 1) ? Qt  : (z == 2) ? Vf  : qpt;
    const int    tr = (z == 2) ? 0 : 1;

    const int lane = threadIdx.x & 63;
    const int w    = threadIdx.x >> 6;
    const int c16 = lane & 15, q4 = lane >> 4;
    const int n0 = (blockIdx.x * 4 + w) * 64;
    const int b  = blockIdx.y;

    bf16x8 wa[4][2];
    #pragma unroll
    for (int to = 0; to < 4; ++to)
        #pragma unroll
        for (int h = 0; h < 2; ++h) {
            const float* wp = W + (16 * to + c16) * 64 + q4 * 8 + 32 * h;
            float4 f0 = *(const float4*)wp;
            float4 f1 = *(const float4*)(wp + 4);
            bf16 tmp[8] = {(bf16)f0.x, (bf16)f0.y, (bf16)f0.z, (bf16)f0.w,
                           (bf16)f1.x, (bf16)f1.y, (bf16)f1.z, (bf16)f1.w};
            wa[to][h] = *(bf16x8*)tmp;
        }

    f32x4 acc[4][4];
    #pragma unroll
    for (int to = 0; to < 4; ++to)
        #pragma unroll
        for (int tn = 0; tn < 4; ++tn) acc[to][tn] = (f32x4){0.f, 0.f, 0.f, 0.f};

    #pragma unroll
    for (int tn = 0; tn < 4; ++tn) {
        const bf16* xrow = XT + ((size_t)b * N + n0 + 16 * tn + c16) * 64 + q4 * 8;
        bf16x8 xb0 = *(const bf16x8*)xrow;
        bf16x8 xb1 = *(const bf16x8*)(xrow + 32);
        #pragma unroll
        for (int to = 0; to < 4; ++to) {
            acc[to][tn] = __builtin_amdgcn_mfma_f32_16x16x32_bf16(wa[to][0], xb0, acc[to][tn], 0, 0, 0);
            acc[to][tn] = __builtin_amdgcn_mfma_f32_16x16x32_bf16(wa[to][1], xb1, acc[to][tn], 0, 0, 0);
        }
    }

    #pragma unroll
    for (int to = 0; to < 4; ++to) {
        float4 b4 = *(const float4*)(Bs + 16 * to + q4 * 4);
        float bias[4] = {b4.x, b4.y, b4.z, b4.w};
        #pragma unroll
        for (int tn = 0; tn < 4; ++tn) {
            if (tr) {
                bf16 yv[4];
                #pragma unroll
                for (int r = 0; r < 4; ++r) yv[r] = (bf16)(acc[to][tn][r] + bias[r]);
                *(bf16x4*)(Y + ((size_t)b * N + n0 + 16 * tn + c16) * 64 + 16 * to + q4 * 4) = *(bf16x4*)yv;
            } else {
                #pragma unroll
                for (int r = 0; r < 4; ++r)
                    Y[((size_t)b * 64 + 16 * to + q4 * 4 + r) * N + n0 + 16 * tn + c16] =
                        (bf16)(acc[to][tn][r] + bias[r]);
            }
        }
    }
}

// ---------------------------------------------------------------------------
// Flash, S^T/O^T, 32 queries/wave, 128/block.
//   Qt: (B,NQ,64), Kt: (B,L,64), Vn: (B,64,L) bf16.
//   PLAYOUT=1: Opart (B,S,NQ,64). PLAYOUT=0: (B,S,64,NQ).
// ---------------------------------------------------------------------------
template<int NSPLIT, int PLAYOUT>
__global__ __launch_bounds__(256) void flash_kernel(
    const bf16* __restrict__ Qt, const bf16* __restrict__ Kt,
    const bf16* __restrict__ Vn, int NQ, int L,
    float* __restrict__ Opart, float* __restrict__ Mbuf, float* __restrict__ Lbuf)
{
    const int tid  = threadIdx.x;
    const int lane = tid & 63;
    const int w    = tid >> 6;
    const int c16  = lane & 15;
    const int q4   = lane >> 4;
    const int b    = blockIdx.y;
    const int n0   = blockIdx.x * 128 + w * 32;
    const int s    = blockIdx.z;
    const int SL   = L / NSPLIT;
    const int k0   = s * SL;
    const int ntiles = SL / 64;

    __shared__ __align__(16) bf16 Ks[2][64 * 72];
    __shared__ __align__(16) bf16 Vs[2][64 * 72];
    __shared__ __align__(16) bf16 Pw[4][32 * 72];   // per-wave P buffer

    const int srow = tid >> 2;
    const int scol = (tid & 3) * 16;

    const bf16* Kb = Kt + (size_t)b * L * 64;
    const bf16* Vb = Vn + (size_t)b * 64 * L;

    // Q B-frags, two query sets u=0,1 (n = n0 + 16u + c16)
    bf16x8 bq[2][2];
    #pragma unroll
    for (int u = 0; u < 2; ++u) {
        const bf16* qrow = Qt + ((size_t)b * NQ + n0 + 16 * u + c16) * 64 + q4 * 8;
        bq[u][0] = *(const bf16x8*)(qrow);
        bq[u][1] = *(const bf16x8*)(qrow + 32);
    }

    f32x4 O[2][4];
    #pragma unroll
    for (int u = 0; u < 2; ++u)
        #pragma unroll
        for (int g = 0; g < 4; ++g) O[u][g] = (f32x4){0.f, 0.f, 0.f, 0.f};
    float m_run[2] = {-INFINITY, -INFINITY};
    float l_run[2] = {0.f, 0.f};

    // stage tile 0
    {
        const bf16* kg = Kb + ((size_t)(k0 + srow)) * 64 + scol;
        *(bf16x8*)&Ks[0][srow * 72 + scol]     = *(const bf16x8*)kg;
        *(bf16x8*)&Ks[0][srow * 72 + scol + 8] = *(const bf16x8*)(kg + 8);
        const bf16* vg = Vb + (size_t)srow * L + k0 + scol;
        *(bf16x8*)&Vs[0][srow * 72 + scol]     = *(const bf16x8*)vg;
        *(bf16x8*)&Vs[0][srow * 72 + scol + 8] = *(const bf16x8*)(vg + 8);
    }
    __syncthreads();

    for (int it = 0; it < ntiles; ++it) {
        const int buf = it & 1;
        if (it + 1 < ntiles) {
            const int kn = k0 + (it + 1) * 64;
            const bf16* kg = Kb + ((size_t)(kn + srow)) * 64 + scol;
            *(bf16x8*)&Ks[buf ^ 1][srow * 72 + scol]     = *(const bf16x8*)kg;
            *(bf16x8*)&Ks[buf ^ 1][srow * 72 + scol + 8] = *(const bf16x8*)(kg + 8);
            const bf16* vg = Vb + (size_t)srow * L + kn + scol;
            *(bf16x8*)&Vs[buf ^ 1][srow * 72 + scol]     = *(const bf16x8*)vg;
            *(bf16x8*)&Vs[buf ^ 1][srow * 72 + scol + 8] = *(const bf16x8*)(vg + 8);
        }

        // ---- S^T for both query sets, K-frags shared ----
        f32x4 sv[2][4];
        #pragma unroll
        for (int t = 0; t < 4; ++t) {
            const bf16* krow = &Ks[buf][(16 * t + c16) * 72 + q4 * 8];
            bf16x8 ak0 = *(const bf16x8*)(krow);
            bf16x8 ak1 = *(const bf16x8*)(krow + 32);
            #pragma unroll
            for (int u = 0; u < 2; ++u) {
                f32x4 z = (f32x4){0.f, 0.f, 0.f, 0.f};
                z = __builtin_amdgcn_mfma_f32_16x16x32_bf16(ak0, bq[u][0], z, 0, 0, 0);
                sv[u][t] = __builtin_amdgcn_mfma_f32_16x16x32_bf16(ak1, bq[u][1], z, 0, 0, 0);
            }
        }

        // ---- per-lane softmax stats; P to private LDS ----
        #pragma unroll
        for (int u = 0; u < 2; ++u) {
            float mx = sv[u][0][0];
            #pragma unroll
            for (int t = 0; t < 4; ++t)
                #pragma unroll
                for (int r = 0; r < 4; ++r) mx = fmaxf(mx, sv[u][t][r]);
            mx = fmaxf(mx, __shfl_xor(mx, 16));
            mx = fmaxf(mx, __shfl_xor(mx, 32));
            float nm = fmaxf(m_run[u], mx);
            float alpha = __expf(m_run[u] - nm);
            m_run[u] = nm;

            float ls = 0.f;
            #pragma unroll
            for (int t = 0; t < 4; ++t)
                #pragma unroll
                for (int r = 0; r < 4; ++r) {
                    float p = __expf(sv[u][t][r] - nm);
                    sv[u][t][r] = p;
                    ls += p;
                }
            ls += __shfl_xor(ls, 16);
            ls += __shfl_xor(ls, 32);
            l_run[u] = l_run[u] * alpha + ls;
            #pragma unroll
            for (int g = 0; g < 4; ++g)
                #pragma unroll
                for (int r = 0; r < 4; ++r) O[u][g][r] *= alpha;

            #pragma unroll
            for (int t = 0; t < 4; ++t) {
                bf16x4 pv;
                pv[0] = (bf16)sv[u][t][0]; pv[1] = (bf16)sv[u][t][1];
                pv[2] = (bf16)sv[u][t][2]; pv[3] = (bf16)sv[u][t][3];
                *(bf16x4*)&Pw[w][(16 * u + c16) * 72 + 16 * t + 4 * q4] = pv;
            }
        }

        // ---- PV: V-frags shared across both query sets ----
        #pragma unroll
        for (int h = 0; h < 2; ++h) {
            bf16x8 pf0 = *(const bf16x8*)&Pw[w][(c16) * 72 + 32 * h + 8 * q4];
            bf16x8 pf1 = *(const bf16x8*)&Pw[w][(16 + c16) * 72 + 32 * h + 8 * q4];
            #pragma unroll
            for (int g = 0; g < 4; ++g) {
                bf16x8 av = *(const bf16x8*)&Vs[buf][(16 * g + c16) * 72 + 32 * h + q4 * 8];
                O[0][g] = __builtin_amdgcn_mfma_f32_16x16x32_bf16(av, pf0, O[0][g], 0, 0, 0);
                O[1][g] = __builtin_amdgcn_mfma_f32_16x16x32_bf16(av, pf1, O[1][g], 0, 0, 0);
            }
        }
        __syncthreads();
    }

    if (PLAYOUT == 1) {
        #pragma unroll
        for (int u = 0; u < 2; ++u) {
            float* dst = Opart + ((size_t)(b * NSPLIT + s) * NQ + n0 + 16 * u + c16) * 64 + q4 * 4;
            #pragma unroll
            for (int g = 0; g < 4; ++g) *(f32x4*)(dst + 16 * g) = O[u][g];
        }
    } else {
        #pragma unroll
        for (int u = 0; u < 2; ++u)
            #pragma unroll
            for (int g = 0; g < 4; ++g)
                #pragma unroll
                for (int r = 0; r < 4; ++r)
                    Opart[((size_t)(b * NSPLIT + s) * 64 + 16 * g + 4 * q4 + r) * NQ + n0 + 16 * u + c16] = O[u][g][r];
    }
    if (lane < 16) {
        #pragma unroll
        for (int u = 0; u < 2; ++u) {
            Mbuf[(b * NSPLIT + s) * NQ + n0 + 16 * u + lane] = m_run[u];
            Lbuf[(b * NSPLIT + s) * NQ + n0 + 16 * u + lane] = l_run[u];
        }
    }
}

// ---------------------------------------------------------------------------
// Fused: combine stage-1 partials (8 splits, row-major) -> bf16 tile in LDS,
// then k (transposed) and v (normal) projections of it. Block = 64 rows of out1.
// ---------------------------------------------------------------------------
__global__ __launch_bounds__(256) void comb1kv_kernel(
    const float* __restrict__ Opart, const float* __restrict__ Mbuf,
    const float* __restrict__ Lbuf,
    const float* __restrict__ w_k, const float* __restrict__ b_k, bf16* __restrict__ kpt,
    const float* __restrict__ w_v, const float* __restrict__ b_v, bf16* __restrict__ vp)
{
    __shared__ __align__(16) bf16 tile[64 * 72];
    __shared__ float wbuf[64 * 8];
    const int t  = threadIdx.x;
    const int m0 = blockIdx.x * 64;
    const int b  = blockIdx.y;

    if (t < 64) {
        int m = m0 + t;
        float ms[8], ls[8];
        #pragma unroll
        for (int s = 0; s < 8; ++s) {
            ms[s] = Mbuf[(b * 8 + s) * 1024 + m];
            ls[s] = Lbuf[(b * 8 + s) * 1024 + m];
        }
        float M = ms[0];
        #pragma unroll
        for (int s = 1; s < 8; ++s) M = fmaxf(M, ms[s]);
        float wsv[8], lt = 0.f;
        #pragma unroll
        for (int s = 0; s < 8; ++s) { wsv[s] = __expf(ms[s] - M); lt += ls[s] * wsv[s]; }
        float inv = 1.f / lt;
        #pragma unroll
        for (int s = 0; s < 8; ++s) wbuf[t * 8 + s] = wsv[s] * inv;
    }
    __syncthreads();

    #pragma unroll
    for (int i = 0; i < 4; ++i) {
        int ml = i * 16 + (t >> 4);
        int c4 = (t & 15) * 4;
        const float* base = Opart + ((size_t)(b * 8) * 1024 + m0 + ml) * 64 + c4;
        float a0 = 0.f, a1 = 0.f, a2 = 0.f, a3 = 0.f;
        #pragma unroll
        for (int s = 0; s < 8; ++s) {
            f32x4 v = *(const f32x4*)(base + (size_t)s * 1024 * 64);
            float wg = wbuf[ml * 8 + s];
            a0 += v[0] * wg; a1 += v[1] * wg; a2 += v[2] * wg; a3 += v[3] * wg;
        }
        bf16x4 o; o[0] = (bf16)a0; o[1] = (bf16)a1; o[2] = (bf16)a2; o[3] = (bf16)a3;
        *(bf16x4*)&tile[ml * 72 + c4] = o;
    }
    __syncthreads();

    const int lane = t & 63;
    const int w    = t >> 6;
    const int c16 = lane & 15, q4 = lane >> 4;

    if (w < 2) {
        // kpt[n][o]: A = tile rows n, B = w_k rows o
        bf16x8 wb[4][2];
        #pragma unroll
        for (int to = 0; to < 4; ++to)
            #pragma unroll
            for (int h = 0; h < 2; ++h) {
                const float* wp = w_k + (16 * to + c16) * 64 + q4 * 8 + 32 * h;
                float4 f0 = *(const float4*)wp;
                float4 f1 = *(const float4*)(wp + 4);
                bf16 tmp[8] = {(bf16)f0.x, (bf16)f0.y, (bf16)f0.z, (bf16)f0.w,
                               (bf16)f1.x, (bf16)f1.y, (bf16)f1.z, (bf16)f1.w};
                wb[to][h] = *(bf16x8*)tmp;
            }
        #pragma unroll
        for (int tm2 = 0; tm2 < 2; ++tm2) {
            int tm = w * 2 + tm2;
            bf16x8 a0 = *(const bf16x8*)&tile[(16 * tm + c16) * 72 + q4 * 8];
            bf16x8 a1 = *(const bf16x8*)&tile[(16 * tm + c16) * 72 + q4 * 8 + 32];
            #pragma unroll
            for (int to = 0; to < 4; ++to) {
                f32x4 acc = (f32x4){0.f, 0.f, 0.f, 0.f};
                acc = __builtin_amdgcn_mfma_f32_16x16x32_bf16(a0, wb[to][0], acc, 0, 0, 0);
                acc = __builtin_amdgcn_mfma_f32_16x16x32_bf16(a1, wb[to][1], acc, 0, 0, 0);
                float bias = b_k[16 * to + c16];
                #pragma unroll
                for (int r = 0; r < 4; ++r)
                    kpt[((size_t)b * 1024 + m0 + 16 * tm + 4 * q4 + r) * 64 + 16 * to + c16] =
                        (bf16)(acc[r] + bias);
            }
        }
    } else {
        // vp[c][m]: A = w_v rows c, B = tile rows m (as cols)
        bf16x8 wa[4][2];
        #pragma unroll
        for (int ta = 0; ta < 4; ++ta)
            #pragma unroll
            for (int h = 0; h < 2; ++h) {
                const float* wp = w_v + (16 * ta + c16) * 64 + q4 * 8 + 32 * h;
                float4 f0 = *(const float4*)wp;
                float4 f1 = *(const float4*)(wp + 4);
                bf16 tmp[8] = {(bf16)f0.x, (bf16)f0.y, (bf16)f0.z, (bf16)f0.w,
                               (bf16)f1.x, (bf16)f1.y, (bf16)f1.z, (bf16)f1.w};
                wa[ta][h] = *(bf16x8*)tmp;
            }
        #pragma unroll
        for (int tm2 = 0; tm2 < 2; ++tm2) {
            int tm = (w - 2) * 2 + tm2;
            bf16x8 bb0 = *(const bf16x8*)&tile[(16 * tm + c16) * 72 + q4 * 8];
            bf16x8 bb1 = *(const bf16x8*)&tile[(16 * tm + c16) * 72 + q4 * 8 + 32];
            #pragma unroll
            for (int ta = 0; ta < 4; ++ta) {
                f32x4 acc = (f32x4){0.f, 0.f, 0.f, 0.f};
                acc = __builtin_amdgcn_mfma_f32_16x16x32_bf16(wa[ta][0], bb0, acc, 0, 0, 0);
                acc = __builtin_amdgcn_mfma_f32_16x16x32_bf16(wa[ta][1], bb1, acc, 0, 0, 0);
                float4 b4 = *(const float4*)(b_v + 16 * ta + 4 * q4);
                float bias[4] = {b4.x, b4.y, b4.z, b4.w};
                #pragma unroll
                for (int r = 0; r < 4; ++r)
                    vp[((size_t)b * 64 + 16 * ta + 4 * q4 + r) * 1024 + m0 + 16 * tm + c16] =
                        (bf16)(acc[r] + bias[r]);
            }
        }
    }
}

// ---------------------------------------------------------------------------
// Combine stage-2 partials (2 splits, channel-major) + gamma + residual.
// ---------------------------------------------------------------------------
__global__ __launch_bounds__(256) void combine2_kernel(
    const float* __restrict__ Opart, const float* __restrict__ Mbuf,
    const float* __restrict__ Lbuf, const float* __restrict__ x,
    const float* __restrict__ gamma_p, float* __restrict__ out)
{
    int idx = blockIdx.x * 256 + threadIdx.x;
    int n = idx & 4095;
    int b = idx >> 18;
    float m0 = Mbuf[(b * 2 + 0) * 4096 + n], m1 = Mbuf[(b * 2 + 1) * 4096 + n];
    float l0 = Lbuf[(b * 2 + 0) * 4096 + n], l1 = Lbuf[(b * 2 + 1) * 4096 + n];
    float M = fmaxf(m0, m1);
    float w0 = __expf(m0 - M), w1 = __expf(m1 - M);
    float lt = l0 * w0 + l1 * w1;
    int c = (idx >> 12) & 63;
    float acc = Opart[((size_t)(b * 2 + 0) * 64 + c) * 4096 + n] * w0
              + Opart[((size_t)(b * 2 + 1) * 64 + c) * 4096 + n] * w1;
    out[idx] = gamma_p[0] * (acc / lt) + x[idx];
}

// ---------------------------------------------------------------------------
extern "C" void kernel_launch(void* const* d_in, const int* in_sizes, int n_in,
                              void* d_out, int out_size, void* d_ws, size_t ws_size,
                              hipStream_t stream) {
    const float* x    = (const float*)d_in[0];
    const float* w_q  = (const float*)d_in[1];
    const float* b_q  = (const float*)d_in[2];
    const float* w_K  = (const float*)d_in[3];
    const float* b_K  = (const float*)d_in[4];
    const float* w_V  = (const float*)d_in[5];
    const float* b_V  = (const float*)d_in[6];
    const float* w_Q  = (const float*)d_in[7];
    const float* b_Q  = (const float*)d_in[8];
    const float* w_k  = (const float*)d_in[9];
    const float* b_k  = (const float*)d_in[10];
    const float* w_v  = (const float*)d_in[11];
    const float* b_v  = (const float*)d_in[12];
    const float* gamma = (const float*)d_in[13];
    float* out = (float*)d_out;

    char* ws = (char*)d_ws;
    bf16*  xT    = (bf16*)ws;   ws += (size_t)8 * 4096 * 64 * 2;
    bf16*  Kt    = (bf16*)ws;   ws += (size_t)8 * 4096 * 64 * 2;
    bf16*  Qt    = (bf16*)ws;   ws += (size_t)8 * 4096 * 64 * 2;
    bf16*  Vf    = (bf16*)ws;   ws += (size_t)8 * 4096 * 64 * 2;
    bf16*  xpT   = (bf16*)ws;   ws += (size_t)8 * 1024 * 64 * 2;
    bf16*  qpt   = (bf16*)ws;   ws += (size_t)8 * 1024 * 64 * 2;
    bf16*  kpt   = (bf16*)ws;   ws += (size_t)8 * 1024 * 64 * 2;
    bf16*  vp    = (bf16*)ws;   ws += (size_t)8 * 64 * 1024 * 2;
    float* Opart = (float*)ws;  ws += (size_t)8 * 8 * 1024 * 64 * 4;   // shared by both stages
    float* Mb    = (float*)ws;  ws += (size_t)8 * 8 * 1024 * 4;
    float* Lb    = (float*)ws;  ws += (size_t)8 * 8 * 1024 * 4;

    // 1) transpose-cast + pool
    transpool_kernel<<<dim3(32, 8), 256, 0, stream>>>(x, xT, xpT);

    // 2) all projections (K,Q,V of xT; q of xpT)
    proj_all_kernel<<<dim3(16, 8, 4), 256, 0, stream>>>(
        xT, xpT, w_K, b_K, Kt, w_Q, b_Q, Qt, w_V, b_V, Vf, w_q, b_q, qpt);

    // 3) stage-1 flash: qpt (1024 q) vs Kt/Vf (L=4096), split x8
    flash_kernel<8, 1><<<dim3(8, 8, 8), 256, 0, stream>>>(
        qpt, Kt, Vf, 1024, 4096, Opart, Mb, Lb);

    // 4) fused combine + k,v projections
    comb1kv_kernel<<<dim3(16, 8), 256, 0, stream>>>(
        Opart, Mb, Lb, w_k, b_k, kpt, w_v, b_v, vp);

    // 5) stage-2 flash: Qt (4096 q) vs kpt/vp (L=1024), split x2
    flash_kernel<2, 0><<<dim3(32, 8, 2), 256, 0, stream>>>(
        Qt, kpt, vp, 4096, 1024, Opart, Mb, Lb);

    // 6) combine + gamma + residual
    combine2_kernel<<<8192, 256, 0, stream>>>(Opart, Mb, Lb, x, gamma, out);
}